// Round 1
// baseline (781.313 us; speedup 1.0000x reference)
//
#include <hip/hip_runtime.h>

// SimpleNet: per-pixel MLP over B=4, C=3, H=W=1024 fp32 images.
//   h = tanh(W_in[25x3] @ x)          (per pixel)
//   6x: h = tanh(W[25x25] @ h)
//   out = sigmoid(W_out[3x25] @ h)
// Layout: x, out are [B, C, H, W] -> channel stride HW, pixel index p = b*HW + hw.

#define HW_PIX (1024 * 1024)
#define NPIX   (4 * HW_PIX)
#define HID    25
#define DEPTH  6

// tanh(x) = 1 - 2/(exp(2x)+1);  exp(2x) = exp2(x * 2*log2(e))
// Saturation: exp2 -> inf => rcp -> 0 => +1;  exp2 -> 0 => rcp(1)=1 => -1.  Correct.
__device__ __forceinline__ float fast_tanh(float x) {
    float e = __builtin_amdgcn_exp2f(x * 2.8853900817779268f);  // v_exp_f32
    float r = __builtin_amdgcn_rcpf(e + 1.0f);                  // v_rcp_f32
    return fmaf(-2.0f, r, 1.0f);
}

// sigmoid(x) = 1/(1+exp(-x));  exp(-x) = exp2(-x*log2(e))
__device__ __forceinline__ float fast_sigmoid(float x) {
    float e = __builtin_amdgcn_exp2f(x * -1.4426950408889634f);
    return __builtin_amdgcn_rcpf(e + 1.0f);
}

__global__ __launch_bounds__(256) void simplenet_kernel(
    const float* __restrict__ x,      // [4,3,1024,1024]
    const float* __restrict__ w_in,   // [25,3]
    const float* __restrict__ ws,     // [6,25,25]
    const float* __restrict__ w_out,  // [3,25]
    float* __restrict__ out)          // [4,3,1024,1024]
{
    const int p  = blockIdx.x * 256 + threadIdx.x;   // pixel id, exact grid
    const int b  = p >> 20;                          // p / HW
    const int hw = p & (HW_PIX - 1);

    const float* xb = x + (size_t)b * 3 * HW_PIX + hw;
    const float x0 = xb[0 * HW_PIX];
    const float x1 = xb[1 * HW_PIX];
    const float x2 = xb[2 * HW_PIX];

    float h[HID];

    // input layer: 25x3
#pragma unroll
    for (int o = 0; o < HID; ++o) {
        float acc = w_in[o * 3 + 0] * x0;
        acc = fmaf(w_in[o * 3 + 1], x1, acc);
        acc = fmaf(w_in[o * 3 + 2], x2, acc);
        h[o] = fast_tanh(acc);
    }

    // 6 hidden layers: 25x25. Weight indices are thread-uniform -> s_load.
    for (int l = 0; l < DEPTH; ++l) {
        const float* __restrict__ wl = ws + l * HID * HID;
        float nh[HID];
#pragma unroll
        for (int o = 0; o < HID; ++o) {
            float acc = 0.0f;
#pragma unroll
            for (int c = 0; c < HID; ++c)
                acc = fmaf(wl[o * HID + c], h[c], acc);
            nh[o] = acc;
        }
#pragma unroll
        for (int o = 0; o < HID; ++o)
            h[o] = fast_tanh(nh[o]);
    }

    // output layer: 3x25 + sigmoid
    float* ob = out + (size_t)b * 3 * HW_PIX + hw;
#pragma unroll
    for (int o = 0; o < 3; ++o) {
        float acc = 0.0f;
#pragma unroll
        for (int c = 0; c < HID; ++c)
            acc = fmaf(w_out[o * HID + c], h[c], acc);
        ob[o * HW_PIX] = fast_sigmoid(acc);
    }
}

extern "C" void kernel_launch(void* const* d_in, const int* in_sizes, int n_in,
                              void* d_out, int out_size, void* d_ws, size_t ws_size,
                              hipStream_t stream) {
    const float* x     = (const float*)d_in[0];
    const float* w_in  = (const float*)d_in[1];
    const float* ws    = (const float*)d_in[2];
    const float* w_out = (const float*)d_in[3];
    float* out         = (float*)d_out;

    const int threads = 256;
    const int blocks  = NPIX / threads;  // 16384, exact
    hipLaunchKernelGGL(simplenet_kernel, dim3(blocks), dim3(threads), 0, stream,
                       x, w_in, ws, w_out, out);
}

// Round 2
// 433.010 us; speedup vs baseline: 1.8044x; 1.8044x over previous
//
#include <hip/hip_runtime.h>

// SimpleNet: per-pixel MLP over B=4, C=3, H=W=1024 fp32 images.
//   h = tanh(W_in[25x3] @ x); 6x: h = tanh(W[25x25] @ h); out = sigmoid(W_out[3x25] @ h)
// R2: 2 pixels/thread as <2 x float> to engage v_pk_fma_f32 (fp32 peak needs it),
//     __launch_bounds__(256,1) to stop the 28-VGPR AGPR-spill regalloc seen in R1.

#define HW_PIX (1024 * 1024)
#define NPIX   (4 * HW_PIX)
#define HID    25
#define DEPTH  6

typedef float f2 __attribute__((ext_vector_type(2)));

// tanh(x) = 1 - 2/(exp(2x)+1);  exp(2x) = exp2(x * 2*log2(e)). Saturates correctly.
__device__ __forceinline__ f2 fast_tanh2(f2 x) {
    f2 t = x * 2.8853900817779268f;
    f2 e;
    e.x = __builtin_amdgcn_exp2f(t.x);
    e.y = __builtin_amdgcn_exp2f(t.y);
    f2 d = e + 1.0f;
    f2 r;
    r.x = __builtin_amdgcn_rcpf(d.x);
    r.y = __builtin_amdgcn_rcpf(d.y);
    f2 m2 = -2.0f, one = 1.0f;
    return __builtin_elementwise_fma(m2, r, one);
}

// sigmoid(x) = 1/(1+exp(-x))
__device__ __forceinline__ f2 fast_sigmoid2(f2 x) {
    f2 t = x * -1.4426950408889634f;
    f2 e;
    e.x = __builtin_amdgcn_exp2f(t.x);
    e.y = __builtin_amdgcn_exp2f(t.y);
    f2 d = e + 1.0f;
    f2 r;
    r.x = __builtin_amdgcn_rcpf(d.x);
    r.y = __builtin_amdgcn_rcpf(d.y);
    return r;
}

__global__ __launch_bounds__(256, 1) void simplenet_kernel(
    const float* __restrict__ x,      // [4,3,1024,1024]
    const float* __restrict__ w_in,   // [25,3]
    const float* __restrict__ ws,     // [6,25,25]
    const float* __restrict__ w_out,  // [3,25]
    float* __restrict__ out)          // [4,3,1024,1024]
{
    const int pp  = blockIdx.x * 256 + threadIdx.x;     // pixel-pair id
    const int b   = pp >> 19;                           // (2*pp) / HW
    const int hwp = pp & (HW_PIX / 2 - 1);              // pair index within image

    const f2* xb = (const f2*)(x + (size_t)b * 3 * HW_PIX) + hwp;
    const f2 x0 = xb[0 * (HW_PIX / 2)];
    const f2 x1 = xb[1 * (HW_PIX / 2)];
    const f2 x2 = xb[2 * (HW_PIX / 2)];

    f2 h[HID];

    // input layer: 25x3 (weights are thread-uniform -> s_load, SGPR broadcast)
#pragma unroll
    for (int o = 0; o < HID; ++o) {
        f2 w0 = w_in[o * 3 + 0];
        f2 w1 = w_in[o * 3 + 1];
        f2 w2 = w_in[o * 3 + 2];
        f2 acc = w0 * x0;
        acc = __builtin_elementwise_fma(w1, x1, acc);
        acc = __builtin_elementwise_fma(w2, x2, acc);
        h[o] = fast_tanh2(acc);
    }

    // 6 hidden layers: 25x25
    for (int l = 0; l < DEPTH; ++l) {
        const float* __restrict__ wl = ws + l * HID * HID;
        f2 nh[HID];
#pragma unroll
        for (int o = 0; o < HID; ++o) {
            f2 w0 = wl[o * HID];
            f2 acc = w0 * h[0];
#pragma unroll
            for (int c = 1; c < HID; ++c) {
                f2 wv = wl[o * HID + c];
                acc = __builtin_elementwise_fma(wv, h[c], acc);
            }
            nh[o] = acc;
        }
#pragma unroll
        for (int o = 0; o < HID; ++o)
            h[o] = fast_tanh2(nh[o]);
    }

    // output layer: 3x25 + sigmoid
    f2* ob = (f2*)(out + (size_t)b * 3 * HW_PIX) + hwp;
#pragma unroll
    for (int o = 0; o < 3; ++o) {
        f2 w0 = w_out[o * HID];
        f2 acc = w0 * h[0];
#pragma unroll
        for (int c = 1; c < HID; ++c) {
            f2 wv = w_out[o * HID + c];
            acc = __builtin_elementwise_fma(wv, h[c], acc);
        }
        ob[o * (HW_PIX / 2)] = fast_sigmoid2(acc);
    }
}

extern "C" void kernel_launch(void* const* d_in, const int* in_sizes, int n_in,
                              void* d_out, int out_size, void* d_ws, size_t ws_size,
                              hipStream_t stream) {
    const float* x     = (const float*)d_in[0];
    const float* w_in  = (const float*)d_in[1];
    const float* ws    = (const float*)d_in[2];
    const float* w_out = (const float*)d_in[3];
    float* out         = (float*)d_out;

    const int threads = 256;
    const int blocks  = (NPIX / 2) / threads;  // 8192, exact
    hipLaunchKernelGGL(simplenet_kernel, dim3(blocks), dim3(threads), 0, stream,
                       x, w_in, ws, w_out, out);
}